// Round 8
// baseline (519.234 us; speedup 1.0000x reference)
//
#include <hip/hip_runtime.h>
#include <hip/hip_cooperative_groups.h>
#include <hip/hip_bf16.h>
#include <math.h>

namespace cg = cooperative_groups;

#define N_USERS 100000
#define N_ITEMS 50000
#define N_EDGES 2000000
#define D 64

// Coarse bins: 512 nodes per bin.
#define FB_BINS 98                    // ceil(50000/512)  forward (by item)
#define BB_BINS 196                   // ceil(100000/512) backward (by user)
#define NBINS   (FB_BINS + BB_BINS)   // 294
#define CHUNK   4096                  // edges per binfill chunk
#define NCHUNK  ((N_EDGES + CHUNK - 1) / CHUNK)   // 489
#define FOFF_F_N (FB_BINS * 512 + 1)  // 50177
#define FOFF_B_N (BB_BINS * 512 + 1)  // 100353
#define TOTSLOT  (2 * N_EDGES)
// chain: one cooperative kernel, 512 WGs x 512 thr (2 blocks/CU guaranteed
// by __launch_bounds__(512,4) -> <=128 VGPR; LDS ~4.3KB).
#define CHAIN_WGS 512
#define CHAIN_THR 512
// gathers: 256-thr WGs, 4 waves, 4 nodes per wave = 16 nodes per WG.
#define FWD_WGS (N_ITEMS / 16)        // 3125
#define BWD_WGS ((N_USERS + 15) / 16) // 6250

// ---- bf16 pack/unpack helpers --------------------------------------------
__device__ __forceinline__ float blo(unsigned u) {
    union { unsigned i; float f; } c; c.i = u << 16; return c.f;
}
__device__ __forceinline__ float bhi(unsigned u) {
    union { unsigned i; float f; } c; c.i = u & 0xFFFF0000u; return c.f;
}
__device__ __forceinline__ unsigned bpack(float x, float y) {
    __hip_bfloat16 a = __float2bfloat16(x), b = __float2bfloat16(y);
    unsigned short ua = *reinterpret_cast<unsigned short*>(&a);
    unsigned short ub = *reinterpret_cast<unsigned short*>(&b);
    return (unsigned)ua | ((unsigned)ub << 16);
}

// ---------------------------------------------------------------------------
// gather_run: accumulate bf16 rows tbl[idx*32+q] for idx in stage2[a..b),
// half-wave per edge, 16/8/2/1 unroll ladder (8 rows in flight per lane).
// ---------------------------------------------------------------------------
__device__ __forceinline__ void gather_run(
    const unsigned* __restrict__ tbl, const unsigned* __restrict__ stage2,
    int a, int b, int q, int half, float& ax, float& ay) {
    int k = a;
    for (; k + 16 <= b; k += 16) {
        int s0 = (int)__builtin_nontemporal_load(&stage2[k + half]);
        int s1 = (int)__builtin_nontemporal_load(&stage2[k + 2 + half]);
        int s2 = (int)__builtin_nontemporal_load(&stage2[k + 4 + half]);
        int s3 = (int)__builtin_nontemporal_load(&stage2[k + 6 + half]);
        int s4 = (int)__builtin_nontemporal_load(&stage2[k + 8 + half]);
        int s5 = (int)__builtin_nontemporal_load(&stage2[k + 10 + half]);
        int s6 = (int)__builtin_nontemporal_load(&stage2[k + 12 + half]);
        int s7 = (int)__builtin_nontemporal_load(&stage2[k + 14 + half]);
        unsigned u0 = tbl[(s0 << 5) + q];
        unsigned u1 = tbl[(s1 << 5) + q];
        unsigned u2 = tbl[(s2 << 5) + q];
        unsigned u3 = tbl[(s3 << 5) + q];
        unsigned u4 = tbl[(s4 << 5) + q];
        unsigned u5 = tbl[(s5 << 5) + q];
        unsigned u6 = tbl[(s6 << 5) + q];
        unsigned u7 = tbl[(s7 << 5) + q];
        ax += ((blo(u0) + blo(u1)) + (blo(u2) + blo(u3)))
            + ((blo(u4) + blo(u5)) + (blo(u6) + blo(u7)));
        ay += ((bhi(u0) + bhi(u1)) + (bhi(u2) + bhi(u3)))
            + ((bhi(u4) + bhi(u5)) + (bhi(u6) + bhi(u7)));
    }
    if (k + 8 <= b) {
        int s0 = (int)__builtin_nontemporal_load(&stage2[k + half]);
        int s1 = (int)__builtin_nontemporal_load(&stage2[k + 2 + half]);
        int s2 = (int)__builtin_nontemporal_load(&stage2[k + 4 + half]);
        int s3 = (int)__builtin_nontemporal_load(&stage2[k + 6 + half]);
        unsigned u0 = tbl[(s0 << 5) + q];
        unsigned u1 = tbl[(s1 << 5) + q];
        unsigned u2 = tbl[(s2 << 5) + q];
        unsigned u3 = tbl[(s3 << 5) + q];
        ax += (blo(u0) + blo(u1)) + (blo(u2) + blo(u3));
        ay += (bhi(u0) + bhi(u1)) + (bhi(u2) + bhi(u3));
        k += 8;
    }
    for (; k + 2 <= b; k += 2) {
        unsigned u = tbl[((int)__builtin_nontemporal_load(&stage2[k + half]) << 5) + q];
        ax += blo(u); ay += bhi(u);
    }
    if (k < b && half == 0) {
        unsigned u = tbl[((int)__builtin_nontemporal_load(&stage2[k]) << 5) + q];
        ax += blo(u); ay += bhi(u);
    }
}

// ---------------------------------------------------------------------------
// chain: ONE cooperative kernel for the whole prep pipeline.
//   phase 0: h2b + coarse LDS hist
//   phase 1: WG0 = 294-bin exclusive scan; WG1 = softmax stats
//   phase 2: binfill (chunked coarse scatter)
//   phase 3: redist (balanced fine counting-sort, 196 tasks)
// grid.sync() between phases replaces 3 kernel launches.
// ---------------------------------------------------------------------------
__global__ __launch_bounds__(CHAIN_THR, 4) void chain_kernel(
    const float2* __restrict__ hin, unsigned* __restrict__ hu16,
    const int* __restrict__ src, const int* __restrict__ dst,
    int* __restrict__ gh, int* __restrict__ binoff, int* __restrict__ gcur,
    const float* __restrict__ w, float* __restrict__ stats,
    unsigned* __restrict__ stage, unsigned* __restrict__ stage2,
    int* __restrict__ foff_f, int* __restrict__ foff_b) {
    cg::grid_group grid = cg::this_grid();
    __shared__ int shA[1024];
    __shared__ int shW[8];
    __shared__ float shF[8];
    int tid = threadIdx.x, lane = tid & 63, wv = tid >> 6;
    int bx = blockIdx.x;
    int gs = gridDim.x * CHAIN_THR;
    int g0 = bx * CHAIN_THR + tid;

    // ---- phase 0: h2b + coarse hist -------------------------------------
    for (int i = tid; i < NBINS; i += CHAIN_THR) shA[i] = 0;
    __syncthreads();
    for (int i = g0; i < N_USERS * 32; i += gs) {
        float2 v = hin[i];
        hu16[i] = bpack(v.x, v.y);
    }
    for (int e = g0; e < N_EDGES; e += gs) {
        atomicAdd(&shA[dst[e] >> 9], 1);
        atomicAdd(&shA[FB_BINS + (src[e] >> 9)], 1);
    }
    __syncthreads();
    for (int i = tid; i < NBINS; i += CHAIN_THR) {
        int v = shA[i];
        if (v) atomicAdd(&gh[i], v);
    }
    grid.sync();

    // ---- phase 1: scan (WG0) + softmax stats (WG1) ----------------------
    if (bx == 0) {
        int v = (tid < NBINS) ? gh[tid] : 0;
        int incl = v;
#pragma unroll
        for (int off = 1; off < 64; off <<= 1) {
            int t = __shfl_up(incl, off);
            if (lane >= off) incl += t;
        }
        if (lane == 63) shW[wv] = incl;
        __syncthreads();
        if (wv == 0 && lane < 8) {
            int t = shW[lane];
            int sc = t;
#pragma unroll
            for (int off = 1; off < 8; off <<= 1) {
                int u = __shfl_up(sc, off);
                if (lane >= off) sc += u;
            }
            shW[lane] = sc - t;
        }
        __syncthreads();
        int excl = shW[wv] + incl - v;
        if (tid < NBINS) { binoff[tid] = excl; gcur[tid] = excl; }
        if (tid == NBINS - 1) binoff[NBINS] = excl + v;
    } else if (bx == 1) {
        float m = -INFINITY;
        for (int i = tid; i < N_ITEMS; i += CHAIN_THR) m = fmaxf(m, w[i]);
#pragma unroll
        for (int off = 32; off; off >>= 1) m = fmaxf(m, __shfl_xor(m, off));
        if (lane == 0) shF[wv] = m;
        __syncthreads();
        if (tid == 0) {
            float t = shF[0];
            for (int k = 1; k < 8; k++) t = fmaxf(t, shF[k]);
            shF[0] = t;
        }
        __syncthreads();
        m = shF[0];
        __syncthreads();
        float s = 0.f;
        for (int i = tid; i < N_ITEMS; i += CHAIN_THR) s += expf(w[i] - m);
#pragma unroll
        for (int off = 32; off; off >>= 1) s += __shfl_xor(s, off);
        if (lane == 0) shF[wv] = s;
        __syncthreads();
        if (tid == 0) {
            float t = 0.f;
            for (int k = 0; k < 8; k++) t += shF[k];
            stats[0] = m;
            stats[1] = t;
        }
    }
    grid.sync();

    // ---- phase 2: binfill ------------------------------------------------
    {
        int* cnt   = shA;
        int* gbase = shA + 294;
        int* lcur  = shA + 588;
        for (int c = bx; c < NCHUNK; c += gridDim.x) {
            int base = c * CHUNK;
            int nEdge = N_EDGES - base; if (nEdge > CHUNK) nEdge = CHUNK;
            for (int t = tid; t < NBINS; t += CHAIN_THR) { cnt[t] = 0; lcur[t] = 0; }
            __syncthreads();
            int es[8], ed[8];
#pragma unroll
            for (int j = 0; j < 8; j++) {
                int k = j * CHAIN_THR + tid;
                if (k < nEdge) {
                    es[j] = src[base + k];
                    ed[j] = dst[base + k];
                    atomicAdd(&cnt[ed[j] >> 9], 1);
                    atomicAdd(&cnt[FB_BINS + (es[j] >> 9)], 1);
                } else {
                    es[j] = -1;
                }
            }
            __syncthreads();
            for (int t = tid; t < NBINS; t += CHAIN_THR) {
                int cv = cnt[t];
                gbase[t] = cv ? atomicAdd(&gcur[t], cv) : 0;
            }
            __syncthreads();
#pragma unroll
            for (int j = 0; j < 8; j++) {
                if (es[j] >= 0) {
                    int s = es[j], d = ed[j];
                    int bf = d >> 9;
                    int p = atomicAdd(&lcur[bf], 1);
                    stage[gbase[bf] + p] = (unsigned)s | ((unsigned)(d & 511) << 17);
                    int bb = FB_BINS + (s >> 9);
                    int qq = atomicAdd(&lcur[bb], 1);
                    stage[gbase[bb] + qq] = (unsigned)d | ((unsigned)(s & 511) << 16);
                }
            }
            __syncthreads();
        }
    }
    grid.sync();

    // ---- phase 3: redist (fine counting-sort, 196 balanced tasks) -------
    if (bx < FB_BINS) {
        int B = bx;
        int beg = binoff[B], end = binoff[B + 1];
        shA[tid] = 0;
        __syncthreads();
        for (int k = beg + tid; k < end; k += CHAIN_THR)
            atomicAdd(&shA[(stage[k] >> 17) & 511], 1);
        __syncthreads();
        int v = shA[tid];
        int incl = v;
#pragma unroll
        for (int off = 1; off < 64; off <<= 1) {
            int u = __shfl_up(incl, off);
            if (lane >= off) incl += u;
        }
        if (lane == 63) shW[wv] = incl;
        __syncthreads();
        if (tid == 0) {
            int run = 0;
#pragma unroll
            for (int k2 = 0; k2 < 8; k2++) { int x = shW[k2]; shW[k2] = run; run += x; }
        }
        __syncthreads();
        int base = beg + shW[wv] + incl - v;
        foff_f[(B << 9) | tid] = base;
        shA[tid] = base;
        if (B == FB_BINS - 1 && tid == 0) foff_f[FB_BINS * 512] = end;
        __syncthreads();
        for (int k = beg + tid; k < end; k += CHAIN_THR) {
            unsigned e = stage[k];
            int p = atomicAdd(&shA[(e >> 17) & 511], 1);
            stage2[p] = e & 0x1FFFFu;
        }
    } else if (bx < 196) {
        for (int pass = 0; pass < 2; pass++) {
            int B = FB_BINS + ((bx - FB_BINS) << 1) + pass;
            int beg = binoff[B], end = binoff[B + 1];
            shA[tid] = 0;
            __syncthreads();
            for (int k = beg + tid; k < end; k += CHAIN_THR)
                atomicAdd(&shA[(stage[k] >> 16) & 511], 1);
            __syncthreads();
            int v = shA[tid];
            int incl = v;
#pragma unroll
            for (int off = 1; off < 64; off <<= 1) {
                int u = __shfl_up(incl, off);
                if (lane >= off) incl += u;
            }
            if (lane == 63) shW[wv] = incl;
            __syncthreads();
            if (tid == 0) {
                int run = 0;
#pragma unroll
                for (int k2 = 0; k2 < 8; k2++) { int x = shW[k2]; shW[k2] = run; run += x; }
            }
            __syncthreads();
            int base = beg + shW[wv] + incl - v;
            foff_b[((B - FB_BINS) << 9) | tid] = base;
            shA[tid] = base;
            if (B == NBINS - 1 && tid == 0) foff_b[BB_BINS * 512] = end;
            __syncthreads();
            for (int k = beg + tid; k < end; k += CHAIN_THR) {
                unsigned e = stage[k];
                int p = atomicAdd(&shA[(e >> 16) & 511], 1);
                stage2[p] = e & 0xFFFFu;
            }
            __syncthreads();
        }
    }
}

// ---------------------------------------------------------------------------
// fwd_gather: pure gather (R5-proven: 68.6us), 16 items per 256-thr WG,
// fused epilogue -> bf16 rst.
// ---------------------------------------------------------------------------
__global__ __launch_bounds__(256) void fwd_gather_kernel(
    const unsigned* __restrict__ hu16, const float* __restrict__ pf,
    const float* __restrict__ edge_w, const unsigned* __restrict__ stage2,
    const int* __restrict__ foff_f, const float* __restrict__ stats,
    unsigned* __restrict__ rst16) {
    int tid = threadIdx.x, lane = tid & 63, wv = tid >> 6;
    int q = lane & 31, half = lane >> 5;
    float m = stats[0], ssum = stats[1];
    const float2* PF2 = (const float2*)pf;
    int i0 = blockIdx.x * 16;

    for (int il = wv; il < 16; il += 4) {
        int i = i0 + il;
        if (i >= N_ITEMS) break;
        int a = foff_f[i], b = foff_f[i + 1];
        float ax = 0.f, ay = 0.f;
        gather_run(hu16, stage2, a, b, q, half, ax, ay);
        ax += __shfl_xor(ax, 32);
        ay += __shfl_xor(ay, 32);
        if (half == 0) {
            float deg = (float)(b - a);
            if (deg < 1.f) deg = 1.f;
            float sc = expf(edge_w[i] - m) / (ssum * deg);
            float2 pv = PF2[(size_t)i * 32 + q];
            float vx = (ax + 0.5f * tanhf(pv.x)) * sc;
            float vy = (ay + 0.5f * tanhf(pv.y)) * sc;
            rst16[(size_t)i * 32 + q] = bpack(vx, vy);
        }
    }
}

// ---------------------------------------------------------------------------
// bwd_gather: pure gather over bf16 rst (6.4MB table); fp32 out with deg norm.
// ---------------------------------------------------------------------------
__global__ __launch_bounds__(256) void bwd_gather_kernel(
    const unsigned* __restrict__ rst16, const unsigned* __restrict__ stage2,
    const int* __restrict__ foff_b, float* __restrict__ out) {
    int tid = threadIdx.x, lane = tid & 63, wv = tid >> 6;
    int q = lane & 31, half = lane >> 5;
    float2* OUT2 = (float2*)out;
    int u0i = blockIdx.x * 16;

    for (int il = wv; il < 16; il += 4) {
        int u = u0i + il;
        if (u >= N_USERS) break;
        int a = foff_b[u], b = foff_b[u + 1];
        float ax = 0.f, ay = 0.f;
        gather_run(rst16, stage2, a, b, q, half, ax, ay);
        ax += __shfl_xor(ax, 32);
        ay += __shfl_xor(ay, 32);
        if (half == 0) {
            float deg = (float)(b - a);
            if (deg < 1.f) deg = 1.f;
            OUT2[(size_t)u * 32 + q] = make_float2(ax / deg, ay / deg);
        }
    }
}

// ---------------------------------------------------------------------------
extern "C" void kernel_launch(void* const* d_in, const int* in_sizes, int n_in,
                              void* d_out, int out_size, void* d_ws, size_t ws_size,
                              hipStream_t stream) {
    const float* h_user = (const float*)d_in[0];   // [N_USERS, D]
    const float* pf     = (const float*)d_in[1];   // [N_ITEMS, D]
    const float* edge_w = (const float*)d_in[2];   // [N_ITEMS]
    const int*   src    = (const int*)d_in[3];     // [N_EDGES]
    const int*   dst    = (const int*)d_in[4];     // [N_EDGES]
    float* out = (float*)d_out;                    // [N_USERS, D]

    // workspace carve-up (~54 MB)
    char* p = (char*)d_ws;
    int* gh      = (int*)p;     p += sizeof(int) * NBINS;
    int* binoff  = (int*)p;     p += sizeof(int) * (NBINS + 1);
    int* gcur    = (int*)p;     p += sizeof(int) * NBINS;
    int* foff_f  = (int*)p;     p += sizeof(int) * FOFF_F_N;
    int* foff_b  = (int*)p;     p += sizeof(int) * FOFF_B_N;
    float* stats = (float*)p;   p += 4 * sizeof(float);
    unsigned* stage  = (unsigned*)p; p += sizeof(unsigned) * (size_t)TOTSLOT;
    unsigned* stage2 = (unsigned*)p; p += sizeof(unsigned) * (size_t)TOTSLOT;
    unsigned* hu16   = (unsigned*)p; p += sizeof(unsigned) * (size_t)N_USERS * 32;
    unsigned* rst16  = (unsigned*)p; p += sizeof(unsigned) * (size_t)N_ITEMS * 32;

    hipMemsetAsync(gh, 0, sizeof(int) * NBINS, stream);

    const float2* hin = (const float2*)h_user;
    void* cargs[] = {
        (void*)&hin, (void*)&hu16, (void*)&src, (void*)&dst,
        (void*)&gh, (void*)&binoff, (void*)&gcur,
        (void*)&edge_w, (void*)&stats,
        (void*)&stage, (void*)&stage2, (void*)&foff_f, (void*)&foff_b
    };
    hipLaunchCooperativeKernel((void*)chain_kernel, dim3(CHAIN_WGS), dim3(CHAIN_THR),
                               cargs, 0, stream);

    fwd_gather_kernel<<<FWD_WGS, 256, 0, stream>>>(hu16, pf, edge_w, stage2, foff_f, stats, rst16);
    bwd_gather_kernel<<<BWD_WGS, 256, 0, stream>>>(rst16, stage2, foff_b, out);
}